// Round 5
// baseline (229.139 us; speedup 1.0000x reference)
//
#include <hip/hip_runtime.h>

#define D 128
#define N_GRAPHS 64

typedef unsigned int uint32;
typedef __attribute__((ext_vector_type(8))) _Float16 f16x8;
typedef __attribute__((ext_vector_type(4))) float f32x4;

// fp16 helpers: dword holds 2 fp16 (low = elem 2i, high = elem 2i+1); RNE cvt
__device__ __forceinline__ float hl(uint32 u) {
    return (float)__builtin_bit_cast(_Float16, (unsigned short)(u & 0xFFFF));
}
__device__ __forceinline__ float hh(uint32 u) {
    return (float)__builtin_bit_cast(_Float16, (unsigned short)(u >> 16));
}
__device__ __forceinline__ uint32 h2pair(float a, float b) {
    unsigned short ua = __builtin_bit_cast(unsigned short, (_Float16)a);
    unsigned short ub = __builtin_bit_cast(unsigned short, (_Float16)b);
    return (uint32)ua | ((uint32)ub << 16);
}

// ---------------- prep: zero cnt + pre-convert W1 -> fp16 W^T ----------------
// Replaces the hipMemsetAsync dispatch. Wh[n][kd] holds fp16 pair
// (W1[2kd][n], W1[2kd+1][n]) — the MFMA B-fragment layout, unpadded.
__global__ __launch_bounds__(256) void prep_kernel(int* __restrict__ cnt,
                                                   const float* __restrict__ W1,
                                                   uint32* __restrict__ Wh, int n) {
    int i = blockIdx.x * 256 + threadIdx.x;
    if (i < n) {
        cnt[i] = 0;
    } else if (i < n + D * (D / 2)) {
        int j = i - n;
        int nn = j & 127, kd = j >> 7;  // consecutive threads -> consecutive nn (coalesced reads)
        float v0 = W1[(size_t)(2 * kd) * D + nn];
        float v1 = W1[(size_t)(2 * kd + 1) * D + nn];
        Wh[nn * 64 + kd] = h2pair(v0, v1);
    }
}

// ---------------- fused count_rank + MFMA GEMM (independent, one dispatch) ----
// The 640K-atomic count stretch (~40us) hides the 15-20us gemm. The c-atomics
// are eliminated entirely (R2: 640K device atomics cost ~40us wherever hosted);
// CSR build keeps exactly ONE atomic pass (this one).
// NOTE: rank/cnt must not alias hb (written concurrently by gemm role).

#define GBM 64

__global__ __launch_bounds__(256) void count_gemm_kernel(
    const float* __restrict__ A, const uint32* __restrict__ Wh,
    uint32* __restrict__ hb, int M, int gemmBlocks,
    const int* __restrict__ dst, int* __restrict__ cnt,
    int* __restrict__ rank, int E) {
    __shared__ uint32 lds[64 * 68];  // As 17408B; reused as C staging in epilogue

    if (blockIdx.x >= gemmBlocks) {
        // ---- count role: in-degree + per-edge rank among its dst's edges ----
        int e = (blockIdx.x - gemmBlocks) * 256 + threadIdx.x;
        if (e < E) rank[e] = atomicAdd(&cnt[dst[e]], 1);
        return;
    }

    // ---- gemm role ----
    uint32* As = lds;  // [64 rows][68 dw]
    int tid = threadIdx.x;
    int row0 = blockIdx.x * GBM;

    // stage A tile: 64x128 fp32 -> fp16 (2048 float4, 8/thread, coalesced)
#pragma unroll
    for (int j = 0; j < 8; ++j) {
        int idx = tid + j * 256;
        int r = idx >> 5, c4 = idx & 31;
        float4 v = make_float4(0.f, 0.f, 0.f, 0.f);
        if (row0 + r < M) v = *(const float4*)&A[(size_t)(row0 + r) * D + c4 * 4];
        As[r * 68 + c4 * 2 + 0] = h2pair(v.x, v.y);
        As[r * 68 + c4 * 2 + 1] = h2pair(v.z, v.w);
    }
    __syncthreads();

    int wave = tid >> 6, lane = tid & 63;
    int quad = lane >> 4, l16 = lane & 15;
    int wr = (wave & 1) * 32;   // wave row base (2 m-tiles)
    int wc = (wave >> 1) * 64;  // wave col base (4 n-tiles)
    f32x4 acc[2][4];
#pragma unroll
    for (int mi = 0; mi < 2; ++mi)
#pragma unroll
        for (int ni = 0; ni < 4; ++ni) acc[mi][ni] = (f32x4){0.f, 0.f, 0.f, 0.f};

#pragma unroll
    for (int ks = 0; ks < 4; ++ks) {
        int kd = ks * 16 + quad * 4;  // dword offset of k0 + quad*8 fp16
        f16x8 a0 = *(f16x8*)&As[(wr + l16) * 68 + kd];
        f16x8 a1 = *(f16x8*)&As[(wr + 16 + l16) * 68 + kd];
        f16x8 b0 = *(const f16x8*)&Wh[(wc + l16) * 64 + kd];
        f16x8 b1 = *(const f16x8*)&Wh[(wc + 16 + l16) * 64 + kd];
        f16x8 b2 = *(const f16x8*)&Wh[(wc + 32 + l16) * 64 + kd];
        f16x8 b3 = *(const f16x8*)&Wh[(wc + 48 + l16) * 64 + kd];
        acc[0][0] = __builtin_amdgcn_mfma_f32_16x16x32_f16(a0, b0, acc[0][0], 0, 0, 0);
        acc[0][1] = __builtin_amdgcn_mfma_f32_16x16x32_f16(a0, b1, acc[0][1], 0, 0, 0);
        acc[0][2] = __builtin_amdgcn_mfma_f32_16x16x32_f16(a0, b2, acc[0][2], 0, 0, 0);
        acc[0][3] = __builtin_amdgcn_mfma_f32_16x16x32_f16(a0, b3, acc[0][3], 0, 0, 0);
        acc[1][0] = __builtin_amdgcn_mfma_f32_16x16x32_f16(a1, b0, acc[1][0], 0, 0, 0);
        acc[1][1] = __builtin_amdgcn_mfma_f32_16x16x32_f16(a1, b1, acc[1][1], 0, 0, 0);
        acc[1][2] = __builtin_amdgcn_mfma_f32_16x16x32_f16(a1, b2, acc[1][2], 0, 0, 0);
        acc[1][3] = __builtin_amdgcn_mfma_f32_16x16x32_f16(a1, b3, acc[1][3], 0, 0, 0);
    }
    __syncthreads();  // done reading As; reuse As region as C staging [64][128] fp16

    unsigned short* cs = (unsigned short*)lds;
#pragma unroll
    for (int mi = 0; mi < 2; ++mi)
#pragma unroll
        for (int ni = 0; ni < 4; ++ni)
#pragma unroll
            for (int r = 0; r < 4; ++r) {
                int row = wr + mi * 16 + quad * 4 + r;
                int col2 = wc + ni * 16 + l16;
                cs[row * 128 + col2] =
                    __builtin_bit_cast(unsigned short, (_Float16)acc[mi][ni][r]);
            }
    __syncthreads();
    // coalesced write-out: 64 rows x 16 uint4; C-staging row = 128 fp16 = 64 dwords
#pragma unroll
    for (int j = 0; j < 4; ++j) {
        int idx = tid + j * 256;
        int r = idx >> 4, q = idx & 15;
        if (row0 + r < M)
            *(uint4*)&hb[(size_t)(row0 + r) * 64 + q * 4] = *(uint4*)&lds[r * 64 + q * 4];
    }
}

// ---------------- CSR scan ----------------

// parallel scan, phase A. Fused: dinv.
__global__ __launch_bounds__(1024) void scanA_kernel(const int* __restrict__ cnt,
                                                     int* __restrict__ rowptr,
                                                     int* __restrict__ tot,
                                                     float* __restrict__ dinv, int n) {
    __shared__ int swave[16];
    int t = threadIdx.x;
    int lane = t & 63, wave = t >> 6;
    int i = blockIdx.x * 1024 + t;
    int orig = (i < n) ? cnt[i] : 0;
    int v = orig;
#pragma unroll
    for (int off = 1; off < 64; off <<= 1) {
        int u = __shfl_up(v, off, 64);
        if (lane >= off) v += u;
    }
    if (lane == 63) swave[wave] = v;
    __syncthreads();
    if (wave == 0) {
        int wv = (lane < 16) ? swave[lane] : 0;
#pragma unroll
        for (int off = 1; off < 16; off <<= 1) {
            int u = __shfl_up(wv, off, 64);
            if (lane >= off) wv += u;
        }
        if (lane < 16) swave[lane] = wv;
    }
    if (i < n) dinv[i] = rsqrtf((float)(orig + 1));  // deg = in-deg + self loop
    __syncthreads();
    int incl = v + ((wave > 0) ? swave[wave - 1] : 0);
    if (i < n) rowptr[i] = incl - orig;  // chunk-local exclusive
    if (t == 1023) tot[blockIdx.x] = incl;
}

// phase B: add chunk offsets (<=40 totals: serial per-block prefix is cheap)
__global__ __launch_bounds__(1024) void scanB_kernel(int* __restrict__ rowptr,
                                                     const int* __restrict__ tot,
                                                     int n, int nchunks) {
    __shared__ int soff;
    int b = blockIdx.x, t = threadIdx.x;
    if (t == 0) {
        int o = 0;
        for (int j = 0; j < b; ++j) o += tot[j];
        soff = o;
    }
    __syncthreads();
    int i = b * 1024 + t;
    if (i < n) rowptr[i] += soff;
    if (b == 0 && t == 0) {
        int o = 0;
        for (int j = 0; j < nchunks; ++j) o += tot[j];
        rowptr[n] = o;
    }
}

// fill: pure CSR col scatter (4B/edge), ~5us.
__global__ void fill_kernel(const int* __restrict__ src, const int* __restrict__ dst,
                            const int* __restrict__ rowptr, const int* __restrict__ rank,
                            int* __restrict__ col, int E) {
    int e = blockIdx.x * blockDim.x + threadIdx.x;
    if (e < E) col[rowptr[dst[e]] + rank[e]] = src[e];
}

// ---------------- layer-1 aggregation (gather) + bias + ReLU -> fp16 H1 --------
// fp16 rows: 32-lane group per node, uint2 (8B = 4 fp16) per lane = 256B row/load.
// R4 lesson (tail theory): deg~Poisson(16) means the old scalar remainder loop
// ran ~3.5 DEPENDENT-latency iterations per node — more serial time than the
// batched part. Now a single masked 8-wide loop: index clamped to a valid edge
// (start<end guaranteed inside the loop), weight zeroed for OOB lanes, so all
// 8 row-loads issue in parallel every iteration regardless of degree.

__global__ __launch_bounds__(128) void agg_kernel(const uint32* __restrict__ hb,
                                                  const int* __restrict__ rowptr,
                                                  const int* __restrict__ col,
                                                  const float* __restrict__ dinv,
                                                  const float* __restrict__ bias,
                                                  uint32* __restrict__ h1, int n) {
    int tid = threadIdx.x;
    int lane32 = tid & 31;   // features 4*lane32 .. 4*lane32+3
    int slot = tid >> 5;     // 0..3
    int node = blockIdx.x * 4 + slot;
    if (node >= n) return;
    const uint2* __restrict__ h2 = (const uint2*)hb;  // 32 uint2 per row

    float di = dinv[node];
    float ws = di * di;
    uint2 su = h2[(size_t)node * 32 + lane32];
    float a0 = ws * hl(su.x), a1 = ws * hh(su.x);
    float a2 = ws * hl(su.y), a3 = ws * hh(su.y);

    int start = rowptr[node], end = rowptr[node + 1];
    for (int k = start; k < end; k += 8) {
        uint2 v[8];
        float w[8];
#pragma unroll
        for (int j = 0; j < 8; ++j) {
            int idx = k + j;
            int s = col[idx < end ? idx : start];  // clamped: always a valid edge
            w[j] = (idx < end) ? dinv[s] * di : 0.f;
            v[j] = h2[(size_t)s * 32 + lane32];
        }
#pragma unroll
        for (int j = 0; j < 8; ++j) {
            a0 = fmaf(w[j], hl(v[j].x), a0);
            a1 = fmaf(w[j], hh(v[j].x), a1);
            a2 = fmaf(w[j], hl(v[j].y), a2);
            a3 = fmaf(w[j], hh(v[j].y), a3);
        }
    }

    float4 b4 = ((const float4*)bias)[lane32];
    a0 = fmaxf(a0 + b4.x, 0.f);
    a1 = fmaxf(a1 + b4.y, 0.f);
    a2 = fmaxf(a2 + b4.z, 0.f);
    a3 = fmaxf(a3 + b4.w, 0.f);
    uint2 o;
    o.x = h2pair(a0, a1);
    o.y = h2pair(a2, a3);
    ((uint2*)h1)[(size_t)node * 32 + lane32] = o;
}

// ---------------- layer-2 aggregation: materialize P2[node][128] fp32 ---------
// Same structure as agg (10000-block dynamic balancing — R3 lesson), same
// masked 8-wide batch (R4 tail fix). Pooling is a separate streaming pass.

__global__ __launch_bounds__(128) void agg2_kernel(const uint32* __restrict__ h1,
                                                   const int* __restrict__ rowptr,
                                                   const int* __restrict__ col,
                                                   const float* __restrict__ dinv,
                                                   float* __restrict__ P2, int n) {
    int tid = threadIdx.x;
    int lane32 = tid & 31;
    int slot = tid >> 5;
    int node = blockIdx.x * 4 + slot;
    if (node >= n) return;
    const uint2* __restrict__ h2 = (const uint2*)h1;

    float di = dinv[node];
    float ws = di * di;
    uint2 su = h2[(size_t)node * 32 + lane32];
    float a0 = ws * hl(su.x), a1 = ws * hh(su.x);
    float a2 = ws * hl(su.y), a3 = ws * hh(su.y);

    int start = rowptr[node], end = rowptr[node + 1];
    for (int k = start; k < end; k += 8) {
        uint2 v[8];
        float w[8];
#pragma unroll
        for (int j = 0; j < 8; ++j) {
            int idx = k + j;
            int s = col[idx < end ? idx : start];  // clamped: always a valid edge
            w[j] = (idx < end) ? dinv[s] * di : 0.f;
            v[j] = h2[(size_t)s * 32 + lane32];
        }
#pragma unroll
        for (int j = 0; j < 8; ++j) {
            a0 = fmaf(w[j], hl(v[j].x), a0);
            a1 = fmaf(w[j], hh(v[j].x), a1);
            a2 = fmaf(w[j], hl(v[j].y), a2);
            a3 = fmaf(w[j], hh(v[j].y), a3);
        }
    }

    *(float4*)&P2[(size_t)node * D + lane32 * 4] = make_float4(a0, a1, a2, a3);
}

// ---------------- pooling: segmented streaming sum of P2 by graph -------------
// Block (g, k of PSL): sums slice k of graph g's contiguous node range.
// Fully coalesced; ~20MB total at streaming BW. No gather, no atomics.
#define PSL 16

__global__ __launch_bounds__(128) void pool_kernel(const float* __restrict__ P2,
                                                   const int* __restrict__ batch,
                                                   float* __restrict__ Ppart, int n) {
    __shared__ int srange[2];
    int t = threadIdx.x;
    int g = blockIdx.x >> 4;       // / PSL
    int kslice = blockIdx.x & 15;  // % PSL
    if (t == 0) {
        int lo = 0, hi = n;
        while (lo < hi) { int mid = (lo + hi) >> 1; if (batch[mid] < g) lo = mid + 1; else hi = mid; }
        srange[0] = lo;
        int g1 = g + 1;
        lo = 0; hi = n;
        while (lo < hi) { int mid = (lo + hi) >> 1; if (batch[mid] < g1) lo = mid + 1; else hi = mid; }
        srange[1] = lo;
    }
    __syncthreads();
    int lb = srange[0], cntg = srange[1] - srange[0];
    int a = lb + (int)(((long long)cntg * kslice) >> 4);
    int b = lb + (int)(((long long)cntg * (kslice + 1)) >> 4);

    float s = 0.f;
    int node = a;
    for (; node + 4 <= b; node += 4) {
        float v0 = P2[(size_t)(node + 0) * D + t];
        float v1 = P2[(size_t)(node + 1) * D + t];
        float v2 = P2[(size_t)(node + 2) * D + t];
        float v3 = P2[(size_t)(node + 3) * D + t];
        s += (v0 + v1) + (v2 + v3);
    }
    for (; node < b; ++node) s += P2[(size_t)node * D + t];
    Ppart[(size_t)blockIdx.x * D + t] = s;
}

// epilogue: out[g][f] = rinv_g * (sum_k Ppart[g*PSL+k]) @ W2 + b2
// 256 threads: the PSL partial-sum and the 128-deep W2 dot each split 2-way.
__global__ __launch_bounds__(256) void out_kernel(const float* __restrict__ Ppart,
                                                  const float* __restrict__ W2,
                                                  const float* __restrict__ b2,
                                                  const int* __restrict__ batch, int n,
                                                  float* __restrict__ out) {
    __shared__ float gs[D];
    __shared__ float part[2][D];
    __shared__ float srinv;
    int g = blockIdx.x, t = threadIdx.x;
    int f = t & 127, half = t >> 7;
    if (t == 0) {
        int lo = 0, hi = n;
        while (lo < hi) { int mid = (lo + hi) >> 1; if (batch[mid] < g) lo = mid + 1; else hi = mid; }
        int lb = lo;
        int g1 = g + 1;
        lo = 0; hi = n;
        while (lo < hi) { int mid = (lo + hi) >> 1; if (batch[mid] < g1) lo = mid + 1; else hi = mid; }
        int cg = lo - lb;
        srinv = (cg > 0) ? 1.0f / (float)cg : 0.0f;
    }
    float s = 0.f;
    int j0 = half * (PSL / 2);
#pragma unroll
    for (int j = j0; j < j0 + PSL / 2; ++j)
        s += Ppart[((size_t)g * PSL + j) * D + f];
    part[half][f] = s;
    __syncthreads();
    if (half == 0) gs[f] = part[0][f] + part[1][f];
    __syncthreads();
    float acc = 0.f;
    int k0 = half * (D / 2);
#pragma unroll 8
    for (int k = k0; k < k0 + D / 2; ++k) acc = fmaf(gs[k], W2[k * D + f], acc);
    part[half][f] = acc;
    __syncthreads();
    if (half == 0) {
        float a = part[0][f] + part[1][f];
        float r = srinv;
        out[g * D + f] = (r > 0.f) ? fmaf(a, r, b2[f]) : 0.f;  // empty graph -> 0 (matches ref)
    }
}

// ---------------- launcher ----------------

extern "C" void kernel_launch(void* const* d_in, const int* in_sizes, int n_in,
                              void* d_out, int out_size, void* d_ws, size_t ws_size,
                              hipStream_t stream) {
    const float* x  = (const float*)d_in[0];
    const int*   ei = (const int*)d_in[1];
    const int*   batch = (const int*)d_in[2];
    const float* W1 = (const float*)d_in[3];
    const float* b1 = (const float*)d_in[4];
    const float* W2 = (const float*)d_in[5];
    const float* b2 = (const float*)d_in[6];
    float* out = (float*)d_out;

    const int n = in_sizes[2];       // 40000 nodes
    const int E = in_sizes[1] / 2;   // 640000 edges
    const int* src = ei;             // edge_index[0] = message sources
    const int* dst = ei + E;         // edge_index[1] = aggregation targets

    // workspace carve-up (256B aligned); ws_size ~256MB (poison-fill evidence)
    char* ws = (char*)d_ws;
    size_t off = 0;
    auto carve = [&](size_t bytes) {
        size_t o = off;
        off = (off + bytes + 255) & ~(size_t)255;
        return (void*)(ws + o);
    };
    int*    cnt    = (int*)carve((size_t)n * 4);
    int*    rowptr = (int*)carve((size_t)(n + 1) * 4);
    float*  dinv   = (float*)carve((size_t)n * 4);
    int*    col    = (int*)carve((size_t)E * 4);                 // CSR col (2.56MB)
    uint32* hb     = (uint32*)carve((size_t)n * D * 2);          // fp16 feature rows (10.24MB)
    uint32* h1     = (uint32*)carve((size_t)n * D * 2);          // fp16 H1 rows (10.24MB)
    int*    tot    = (int*)carve(64 * 4);
    int*    rank   = (int*)carve((size_t)E * 4);                 // own carve: gemm role writes
                                                                 // hb WHILE count writes rank
    uint32* Wh     = (uint32*)carve((size_t)D * (D / 2) * 4);    // fp16 W1^T (32KB)
    float*  P2     = (float*)carve((size_t)n * D * 4);           // layer-2 rows fp32 (20.48MB)
    // Ppart (64*PSL*128*4 = 512KB) aliases hb: pool writes it strictly after
    // agg's last read of hb (agg2 reads h1, not hb).
    float*  Ppart  = (float*)hb;
    (void)ws_size;

    const int nchunks = (n + 1023) >> 10;

    // prep replaces the cnt memset dispatch; also builds fp16 W1^T for the gemm
    prep_kernel<<<(n + D * (D / 2) + 255) / 256, 256, 0, stream>>>(cnt, W1, Wh, n);

    // fused dispatch: gemm blocks first, then count blocks (gemm hides under
    // the single remaining 640K-atomic stretch)
    const int gemmBlocks = (n + GBM - 1) / GBM;
    const int countBlocks = (E + 255) / 256;
    count_gemm_kernel<<<gemmBlocks + countBlocks, 256, 0, stream>>>(
        x, Wh, hb, n, gemmBlocks, dst, cnt, rank, E);

    // CSR scan + pure col scatter
    scanA_kernel<<<nchunks, 1024, 0, stream>>>(cnt, rowptr, tot, dinv, n);
    scanB_kernel<<<nchunks, 1024, 0, stream>>>(rowptr, tot, n, nchunks);
    fill_kernel<<<(E + 255) / 256, 256, 0, stream>>>(src, dst, rowptr, rank, col, E);

    // layer 1 aggregation + b1 + ReLU -> h1 (fp16)
    agg_kernel<<<(n + 3) / 4, 128, 0, stream>>>(hb, rowptr, col, dinv, b1, h1, n);

    // layer 2 aggregation (agg-style, materialized) + streaming pool + epilogue
    agg2_kernel<<<(n + 3) / 4, 128, 0, stream>>>(h1, rowptr, col, dinv, P2, n);
    pool_kernel<<<N_GRAPHS * PSL, 128, 0, stream>>>(P2, batch, Ppart, n);
    out_kernel<<<N_GRAPHS, 256, 0, stream>>>(Ppart, W2, b2, batch, n, out);
}

// Round 6
// 195.825 us; speedup vs baseline: 1.1701x; 1.1701x over previous
//
#include <hip/hip_runtime.h>

#define D 128
#define N_GRAPHS 64

typedef unsigned int uint32;
typedef __attribute__((ext_vector_type(8))) _Float16 f16x8;
typedef __attribute__((ext_vector_type(4))) float f32x4;

// fp16 helpers: dword holds 2 fp16 (low = elem 2i, high = elem 2i+1); RNE cvt
__device__ __forceinline__ float hl(uint32 u) {
    return (float)__builtin_bit_cast(_Float16, (unsigned short)(u & 0xFFFF));
}
__device__ __forceinline__ float hh(uint32 u) {
    return (float)__builtin_bit_cast(_Float16, (unsigned short)(u >> 16));
}
__device__ __forceinline__ uint32 h2pair(float a, float b) {
    unsigned short ua = __builtin_bit_cast(unsigned short, (_Float16)a);
    unsigned short ub = __builtin_bit_cast(unsigned short, (_Float16)b);
    return (uint32)ua | ((uint32)ub << 16);
}

// ---------------- prep: zero cnt + pre-convert W1 -> fp16 W^T ----------------
// Replaces the hipMemsetAsync dispatch. Wh[n][kd] holds fp16 pair
// (W1[2kd][n], W1[2kd+1][n]) — the MFMA B-fragment layout, unpadded.
__global__ __launch_bounds__(256) void prep_kernel(int* __restrict__ cnt,
                                                   const float* __restrict__ W1,
                                                   uint32* __restrict__ Wh, int n) {
    int i = blockIdx.x * 256 + threadIdx.x;
    if (i < n) {
        cnt[i] = 0;
    } else if (i < n + D * (D / 2)) {
        int j = i - n;
        int nn = j & 127, kd = j >> 7;  // consecutive threads -> consecutive nn (coalesced reads)
        float v0 = W1[(size_t)(2 * kd) * D + nn];
        float v1 = W1[(size_t)(2 * kd + 1) * D + nn];
        Wh[nn * 64 + kd] = h2pair(v0, v1);
    }
}

// ---------------- fused count_rank + MFMA GEMM (independent, one dispatch) ----
// The 640K-atomic count stretch (~40us) hides the 15-20us gemm. The c-atomics
// are eliminated entirely (R2: 640K device atomics cost ~40us wherever hosted);
// CSR build keeps exactly ONE atomic pass (this one).
// NOTE: rank/cnt must not alias hb (written concurrently by gemm role).

#define GBM 64

__global__ __launch_bounds__(256) void count_gemm_kernel(
    const float* __restrict__ A, const uint32* __restrict__ Wh,
    uint32* __restrict__ hb, int M, int gemmBlocks,
    const int* __restrict__ dst, int* __restrict__ cnt,
    int* __restrict__ rank, int E) {
    __shared__ uint32 lds[64 * 68];  // As 17408B; reused as C staging in epilogue

    if (blockIdx.x >= gemmBlocks) {
        // ---- count role: in-degree + per-edge rank among its dst's edges ----
        int e = (blockIdx.x - gemmBlocks) * 256 + threadIdx.x;
        if (e < E) rank[e] = atomicAdd(&cnt[dst[e]], 1);
        return;
    }

    // ---- gemm role ----
    uint32* As = lds;  // [64 rows][68 dw]
    int tid = threadIdx.x;
    int row0 = blockIdx.x * GBM;

    // stage A tile: 64x128 fp32 -> fp16 (2048 float4, 8/thread, coalesced)
#pragma unroll
    for (int j = 0; j < 8; ++j) {
        int idx = tid + j * 256;
        int r = idx >> 5, c4 = idx & 31;
        float4 v = make_float4(0.f, 0.f, 0.f, 0.f);
        if (row0 + r < M) v = *(const float4*)&A[(size_t)(row0 + r) * D + c4 * 4];
        As[r * 68 + c4 * 2 + 0] = h2pair(v.x, v.y);
        As[r * 68 + c4 * 2 + 1] = h2pair(v.z, v.w);
    }
    __syncthreads();

    int wave = tid >> 6, lane = tid & 63;
    int quad = lane >> 4, l16 = lane & 15;
    int wr = (wave & 1) * 32;   // wave row base (2 m-tiles)
    int wc = (wave >> 1) * 64;  // wave col base (4 n-tiles)
    f32x4 acc[2][4];
#pragma unroll
    for (int mi = 0; mi < 2; ++mi)
#pragma unroll
        for (int ni = 0; ni < 4; ++ni) acc[mi][ni] = (f32x4){0.f, 0.f, 0.f, 0.f};

#pragma unroll
    for (int ks = 0; ks < 4; ++ks) {
        int kd = ks * 16 + quad * 4;  // dword offset of k0 + quad*8 fp16
        f16x8 a0 = *(f16x8*)&As[(wr + l16) * 68 + kd];
        f16x8 a1 = *(f16x8*)&As[(wr + 16 + l16) * 68 + kd];
        f16x8 b0 = *(const f16x8*)&Wh[(wc + l16) * 64 + kd];
        f16x8 b1 = *(const f16x8*)&Wh[(wc + 16 + l16) * 64 + kd];
        f16x8 b2 = *(const f16x8*)&Wh[(wc + 32 + l16) * 64 + kd];
        f16x8 b3 = *(const f16x8*)&Wh[(wc + 48 + l16) * 64 + kd];
        acc[0][0] = __builtin_amdgcn_mfma_f32_16x16x32_f16(a0, b0, acc[0][0], 0, 0, 0);
        acc[0][1] = __builtin_amdgcn_mfma_f32_16x16x32_f16(a0, b1, acc[0][1], 0, 0, 0);
        acc[0][2] = __builtin_amdgcn_mfma_f32_16x16x32_f16(a0, b2, acc[0][2], 0, 0, 0);
        acc[0][3] = __builtin_amdgcn_mfma_f32_16x16x32_f16(a0, b3, acc[0][3], 0, 0, 0);
        acc[1][0] = __builtin_amdgcn_mfma_f32_16x16x32_f16(a1, b0, acc[1][0], 0, 0, 0);
        acc[1][1] = __builtin_amdgcn_mfma_f32_16x16x32_f16(a1, b1, acc[1][1], 0, 0, 0);
        acc[1][2] = __builtin_amdgcn_mfma_f32_16x16x32_f16(a1, b2, acc[1][2], 0, 0, 0);
        acc[1][3] = __builtin_amdgcn_mfma_f32_16x16x32_f16(a1, b3, acc[1][3], 0, 0, 0);
    }
    __syncthreads();  // done reading As; reuse As region as C staging [64][128] fp16

    unsigned short* cs = (unsigned short*)lds;
#pragma unroll
    for (int mi = 0; mi < 2; ++mi)
#pragma unroll
        for (int ni = 0; ni < 4; ++ni)
#pragma unroll
            for (int r = 0; r < 4; ++r) {
                int row = wr + mi * 16 + quad * 4 + r;
                int col2 = wc + ni * 16 + l16;
                cs[row * 128 + col2] =
                    __builtin_bit_cast(unsigned short, (_Float16)acc[mi][ni][r]);
            }
    __syncthreads();
    // coalesced write-out: 64 rows x 16 uint4; C-staging row = 128 fp16 = 64 dwords
#pragma unroll
    for (int j = 0; j < 4; ++j) {
        int idx = tid + j * 256;
        int r = idx >> 4, q = idx & 15;
        if (row0 + r < M)
            *(uint4*)&hb[(size_t)(row0 + r) * 64 + q * 4] = *(uint4*)&lds[r * 64 + q * 4];
    }
}

// ---------------- CSR scan ----------------

// parallel scan, phase A. Fused: dinv.
__global__ __launch_bounds__(1024) void scanA_kernel(const int* __restrict__ cnt,
                                                     int* __restrict__ rowptr,
                                                     int* __restrict__ tot,
                                                     float* __restrict__ dinv, int n) {
    __shared__ int swave[16];
    int t = threadIdx.x;
    int lane = t & 63, wave = t >> 6;
    int i = blockIdx.x * 1024 + t;
    int orig = (i < n) ? cnt[i] : 0;
    int v = orig;
#pragma unroll
    for (int off = 1; off < 64; off <<= 1) {
        int u = __shfl_up(v, off, 64);
        if (lane >= off) v += u;
    }
    if (lane == 63) swave[wave] = v;
    __syncthreads();
    if (wave == 0) {
        int wv = (lane < 16) ? swave[lane] : 0;
#pragma unroll
        for (int off = 1; off < 16; off <<= 1) {
            int u = __shfl_up(wv, off, 64);
            if (lane >= off) wv += u;
        }
        if (lane < 16) swave[lane] = wv;
    }
    if (i < n) dinv[i] = rsqrtf((float)(orig + 1));  // deg = in-deg + self loop
    __syncthreads();
    int incl = v + ((wave > 0) ? swave[wave - 1] : 0);
    if (i < n) rowptr[i] = incl - orig;  // chunk-local exclusive
    if (t == 1023) tot[blockIdx.x] = incl;
}

// phase B: add chunk offsets (<=40 totals: serial per-block prefix is cheap)
__global__ __launch_bounds__(1024) void scanB_kernel(int* __restrict__ rowptr,
                                                     const int* __restrict__ tot,
                                                     int n, int nchunks) {
    __shared__ int soff;
    int b = blockIdx.x, t = threadIdx.x;
    if (t == 0) {
        int o = 0;
        for (int j = 0; j < b; ++j) o += tot[j];
        soff = o;
    }
    __syncthreads();
    int i = b * 1024 + t;
    if (i < n) rowptr[i] += soff;
    if (b == 0 && t == 0) {
        int o = 0;
        for (int j = 0; j < nchunks; ++j) o += tot[j];
        rowptr[n] = o;
    }
}

// fill: pure CSR col scatter (4B/edge), ~5us.
__global__ void fill_kernel(const int* __restrict__ src, const int* __restrict__ dst,
                            const int* __restrict__ rowptr, const int* __restrict__ rank,
                            int* __restrict__ col, int E) {
    int e = blockIdx.x * blockDim.x + threadIdx.x;
    if (e < E) col[rowptr[dst[e]] + rank[e]] = src[e];
}

// ---------------- layer-1 aggregation (gather) + bias + ReLU -> fp16 H1 --------
// fp16 rows: 32-lane group per node, uint2 (8B = 4 fp16) per lane = 256B row/load.
// R5 lesson: the masked always-8-wide loop REGRESSED (agg 38->49us): per-load
// cmp+cndmask on the address path + full-width final iterations cost more than
// the scalar tail ever did. The two-loop shape (x8 batch + scalar tail) is the
// measured optimum — kept. 256-thread blocks (8 node-slots): halves block count
// to probe the 57%-occupancy ceiling seen at 128.

__global__ __launch_bounds__(256) void agg_kernel(const uint32* __restrict__ hb,
                                                  const int* __restrict__ rowptr,
                                                  const int* __restrict__ col,
                                                  const float* __restrict__ dinv,
                                                  const float* __restrict__ bias,
                                                  uint32* __restrict__ h1, int n) {
    int tid = threadIdx.x;
    int lane32 = tid & 31;   // features 4*lane32 .. 4*lane32+3
    int slot = tid >> 5;     // 0..7
    int node = blockIdx.x * 8 + slot;
    if (node >= n) return;
    const uint2* __restrict__ h2 = (const uint2*)hb;  // 32 uint2 per row

    float di = dinv[node];
    float ws = di * di;
    uint2 su = h2[(size_t)node * 32 + lane32];
    float a0 = ws * hl(su.x), a1 = ws * hh(su.x);
    float a2 = ws * hl(su.y), a3 = ws * hh(su.y);

    int k = rowptr[node], end = rowptr[node + 1];
    for (; k + 8 <= end; k += 8) {
        uint2 v[8];
        float w[8];
#pragma unroll
        for (int j = 0; j < 8; ++j) {
            int s = col[k + j];
            w[j] = dinv[s] * di;
            v[j] = h2[(size_t)s * 32 + lane32];
        }
#pragma unroll
        for (int j = 0; j < 8; ++j) {
            a0 = fmaf(w[j], hl(v[j].x), a0);
            a1 = fmaf(w[j], hh(v[j].x), a1);
            a2 = fmaf(w[j], hl(v[j].y), a2);
            a3 = fmaf(w[j], hh(v[j].y), a3);
        }
    }
    for (; k < end; ++k) {
        int s = col[k];
        float w = dinv[s] * di;
        uint2 v = h2[(size_t)s * 32 + lane32];
        a0 = fmaf(w, hl(v.x), a0);
        a1 = fmaf(w, hh(v.x), a1);
        a2 = fmaf(w, hl(v.y), a2);
        a3 = fmaf(w, hh(v.y), a3);
    }

    float4 b4 = ((const float4*)bias)[lane32];
    a0 = fmaxf(a0 + b4.x, 0.f);
    a1 = fmaxf(a1 + b4.y, 0.f);
    a2 = fmaxf(a2 + b4.z, 0.f);
    a3 = fmaxf(a3 + b4.w, 0.f);
    uint2 o;
    o.x = h2pair(a0, a1);
    o.y = h2pair(a2, a3);
    ((uint2*)h1)[(size_t)node * 32 + lane32] = o;
}

// ---------------- layer-2 aggregation: materialize P2[node][128] fp32 ---------
// Same structure as agg (two-loop gather, 256-thread / 8-slot blocks).
// Pooling is a separate streaming pass (pool_kernel).

__global__ __launch_bounds__(256) void agg2_kernel(const uint32* __restrict__ h1,
                                                   const int* __restrict__ rowptr,
                                                   const int* __restrict__ col,
                                                   const float* __restrict__ dinv,
                                                   float* __restrict__ P2, int n) {
    int tid = threadIdx.x;
    int lane32 = tid & 31;
    int slot = tid >> 5;
    int node = blockIdx.x * 8 + slot;
    if (node >= n) return;
    const uint2* __restrict__ h2 = (const uint2*)h1;

    float di = dinv[node];
    float ws = di * di;
    uint2 su = h2[(size_t)node * 32 + lane32];
    float a0 = ws * hl(su.x), a1 = ws * hh(su.x);
    float a2 = ws * hl(su.y), a3 = ws * hh(su.y);

    int k = rowptr[node], end = rowptr[node + 1];
    for (; k + 8 <= end; k += 8) {
        uint2 v[8];
        float w[8];
#pragma unroll
        for (int j = 0; j < 8; ++j) {
            int s = col[k + j];
            w[j] = dinv[s] * di;
            v[j] = h2[(size_t)s * 32 + lane32];
        }
#pragma unroll
        for (int j = 0; j < 8; ++j) {
            a0 = fmaf(w[j], hl(v[j].x), a0);
            a1 = fmaf(w[j], hh(v[j].x), a1);
            a2 = fmaf(w[j], hl(v[j].y), a2);
            a3 = fmaf(w[j], hh(v[j].y), a3);
        }
    }
    for (; k < end; ++k) {
        int s = col[k];
        float w = dinv[s] * di;
        uint2 v = h2[(size_t)s * 32 + lane32];
        a0 = fmaf(w, hl(v.x), a0);
        a1 = fmaf(w, hh(v.x), a1);
        a2 = fmaf(w, hl(v.y), a2);
        a3 = fmaf(w, hh(v.y), a3);
    }

    *(float4*)&P2[(size_t)node * D + lane32 * 4] = make_float4(a0, a1, a2, a3);
}

// ---------------- pooling: segmented streaming sum of P2 by graph -------------
// Block (g, k of PSL): sums slice k of graph g's contiguous node range.
// Fully coalesced; ~20MB total at streaming BW. No gather, no atomics.
#define PSL 16

__global__ __launch_bounds__(128) void pool_kernel(const float* __restrict__ P2,
                                                   const int* __restrict__ batch,
                                                   float* __restrict__ Ppart, int n) {
    __shared__ int srange[2];
    int t = threadIdx.x;
    int g = blockIdx.x >> 4;       // / PSL
    int kslice = blockIdx.x & 15;  // % PSL
    if (t == 0) {
        int lo = 0, hi = n;
        while (lo < hi) { int mid = (lo + hi) >> 1; if (batch[mid] < g) lo = mid + 1; else hi = mid; }
        srange[0] = lo;
        int g1 = g + 1;
        lo = 0; hi = n;
        while (lo < hi) { int mid = (lo + hi) >> 1; if (batch[mid] < g1) lo = mid + 1; else hi = mid; }
        srange[1] = lo;
    }
    __syncthreads();
    int lb = srange[0], cntg = srange[1] - srange[0];
    int a = lb + (int)(((long long)cntg * kslice) >> 4);
    int b = lb + (int)(((long long)cntg * (kslice + 1)) >> 4);

    float s = 0.f;
    int node = a;
    for (; node + 4 <= b; node += 4) {
        float v0 = P2[(size_t)(node + 0) * D + t];
        float v1 = P2[(size_t)(node + 1) * D + t];
        float v2 = P2[(size_t)(node + 2) * D + t];
        float v3 = P2[(size_t)(node + 3) * D + t];
        s += (v0 + v1) + (v2 + v3);
    }
    for (; node < b; ++node) s += P2[(size_t)node * D + t];
    Ppart[(size_t)blockIdx.x * D + t] = s;
}

// epilogue: out[g][f] = rinv_g * (sum_k Ppart[g*PSL+k]) @ W2 + b2
// 256 threads: the PSL partial-sum and the 128-deep W2 dot each split 2-way.
__global__ __launch_bounds__(256) void out_kernel(const float* __restrict__ Ppart,
                                                  const float* __restrict__ W2,
                                                  const float* __restrict__ b2,
                                                  const int* __restrict__ batch, int n,
                                                  float* __restrict__ out) {
    __shared__ float gs[D];
    __shared__ float part[2][D];
    __shared__ float srinv;
    int g = blockIdx.x, t = threadIdx.x;
    int f = t & 127, half = t >> 7;
    if (t == 0) {
        int lo = 0, hi = n;
        while (lo < hi) { int mid = (lo + hi) >> 1; if (batch[mid] < g) lo = mid + 1; else hi = mid; }
        int lb = lo;
        int g1 = g + 1;
        lo = 0; hi = n;
        while (lo < hi) { int mid = (lo + hi) >> 1; if (batch[mid] < g1) lo = mid + 1; else hi = mid; }
        int cg = lo - lb;
        srinv = (cg > 0) ? 1.0f / (float)cg : 0.0f;
    }
    float s = 0.f;
    int j0 = half * (PSL / 2);
#pragma unroll
    for (int j = j0; j < j0 + PSL / 2; ++j)
        s += Ppart[((size_t)g * PSL + j) * D + f];
    part[half][f] = s;
    __syncthreads();
    if (half == 0) gs[f] = part[0][f] + part[1][f];
    __syncthreads();
    float acc = 0.f;
    int k0 = half * (D / 2);
#pragma unroll 8
    for (int k = k0; k < k0 + D / 2; ++k) acc = fmaf(gs[k], W2[k * D + f], acc);
    part[half][f] = acc;
    __syncthreads();
    if (half == 0) {
        float a = part[0][f] + part[1][f];
        float r = srinv;
        out[g * D + f] = (r > 0.f) ? fmaf(a, r, b2[f]) : 0.f;  // empty graph -> 0 (matches ref)
    }
}

// ---------------- launcher ----------------

extern "C" void kernel_launch(void* const* d_in, const int* in_sizes, int n_in,
                              void* d_out, int out_size, void* d_ws, size_t ws_size,
                              hipStream_t stream) {
    const float* x  = (const float*)d_in[0];
    const int*   ei = (const int*)d_in[1];
    const int*   batch = (const int*)d_in[2];
    const float* W1 = (const float*)d_in[3];
    const float* b1 = (const float*)d_in[4];
    const float* W2 = (const float*)d_in[5];
    const float* b2 = (const float*)d_in[6];
    float* out = (float*)d_out;

    const int n = in_sizes[2];       // 40000 nodes
    const int E = in_sizes[1] / 2;   // 640000 edges
    const int* src = ei;             // edge_index[0] = message sources
    const int* dst = ei + E;         // edge_index[1] = aggregation targets

    // workspace carve-up (256B aligned); ws_size ~256MB (poison-fill evidence)
    char* ws = (char*)d_ws;
    size_t off = 0;
    auto carve = [&](size_t bytes) {
        size_t o = off;
        off = (off + bytes + 255) & ~(size_t)255;
        return (void*)(ws + o);
    };
    int*    cnt    = (int*)carve((size_t)n * 4);
    int*    rowptr = (int*)carve((size_t)(n + 1) * 4);
    float*  dinv   = (float*)carve((size_t)n * 4);
    int*    col    = (int*)carve((size_t)E * 4);                 // CSR col (2.56MB)
    uint32* hb     = (uint32*)carve((size_t)n * D * 2);          // fp16 feature rows (10.24MB)
    uint32* h1     = (uint32*)carve((size_t)n * D * 2);          // fp16 H1 rows (10.24MB)
    int*    tot    = (int*)carve(64 * 4);
    int*    rank   = (int*)carve((size_t)E * 4);                 // own carve: gemm role writes
                                                                 // hb WHILE count writes rank
    uint32* Wh     = (uint32*)carve((size_t)D * (D / 2) * 4);    // fp16 W1^T (32KB)
    float*  P2     = (float*)carve((size_t)n * D * 4);           // layer-2 rows fp32 (20.48MB)
    // Ppart (64*PSL*128*4 = 512KB) aliases hb: pool writes it strictly after
    // agg's last read of hb (agg2 reads h1, not hb).
    float*  Ppart  = (float*)hb;
    (void)ws_size;

    const int nchunks = (n + 1023) >> 10;

    // prep replaces the cnt memset dispatch; also builds fp16 W1^T for the gemm
    prep_kernel<<<(n + D * (D / 2) + 255) / 256, 256, 0, stream>>>(cnt, W1, Wh, n);

    // fused dispatch: gemm blocks first, then count blocks (gemm hides under
    // the single remaining 640K-atomic stretch)
    const int gemmBlocks = (n + GBM - 1) / GBM;
    const int countBlocks = (E + 255) / 256;
    count_gemm_kernel<<<gemmBlocks + countBlocks, 256, 0, stream>>>(
        x, Wh, hb, n, gemmBlocks, dst, cnt, rank, E);

    // CSR scan + pure col scatter
    scanA_kernel<<<nchunks, 1024, 0, stream>>>(cnt, rowptr, tot, dinv, n);
    scanB_kernel<<<nchunks, 1024, 0, stream>>>(rowptr, tot, n, nchunks);
    fill_kernel<<<(E + 255) / 256, 256, 0, stream>>>(src, dst, rowptr, rank, col, E);

    // layer 1 aggregation + b1 + ReLU -> h1 (fp16)
    agg_kernel<<<(n + 7) / 8, 256, 0, stream>>>(hb, rowptr, col, dinv, b1, h1, n);

    // layer 2 aggregation (agg-style, materialized) + streaming pool + epilogue
    agg2_kernel<<<(n + 7) / 8, 256, 0, stream>>>(h1, rowptr, col, dinv, P2, n);
    pool_kernel<<<N_GRAPHS * PSL, 128, 0, stream>>>(P2, batch, Ppart, n);
    out_kernel<<<N_GRAPHS, 256, 0, stream>>>(Ppart, W2, b2, batch, n, out);
}

// Round 7
// 195.138 us; speedup vs baseline: 1.1742x; 1.0035x over previous
//
#include <hip/hip_runtime.h>

#define D 128
#define N_GRAPHS 64

typedef unsigned int uint32;
typedef __attribute__((ext_vector_type(8))) _Float16 f16x8;
typedef __attribute__((ext_vector_type(4))) float f32x4;

// fp16 helpers: dword holds 2 fp16 (low = elem 2i, high = elem 2i+1); RNE cvt
__device__ __forceinline__ float hl(uint32 u) {
    return (float)__builtin_bit_cast(_Float16, (unsigned short)(u & 0xFFFF));
}
__device__ __forceinline__ float hh(uint32 u) {
    return (float)__builtin_bit_cast(_Float16, (unsigned short)(u >> 16));
}
__device__ __forceinline__ uint32 h2pair(float a, float b) {
    unsigned short ua = __builtin_bit_cast(unsigned short, (_Float16)a);
    unsigned short ub = __builtin_bit_cast(unsigned short, (_Float16)b);
    return (uint32)ua | ((uint32)ub << 16);
}

// ---------------- prep: zero cnt + pre-convert W1 -> fp16 W^T ----------------
__global__ __launch_bounds__(256) void prep_kernel(int* __restrict__ cnt,
                                                   const float* __restrict__ W1,
                                                   uint32* __restrict__ Wh, int n) {
    int i = blockIdx.x * 256 + threadIdx.x;
    if (i < n) {
        cnt[i] = 0;
    } else if (i < n + D * (D / 2)) {
        int j = i - n;
        int nn = j & 127, kd = j >> 7;  // consecutive threads -> consecutive nn (coalesced reads)
        float v0 = W1[(size_t)(2 * kd) * D + nn];
        float v1 = W1[(size_t)(2 * kd + 1) * D + nn];
        Wh[nn * 64 + kd] = h2pair(v0, v1);
    }
}

// ---------------- fused count_rank + MFMA GEMM (independent, one dispatch) ----
// The 640K-atomic count stretch (~40us) hides the 15-20us gemm. CSR build keeps
// exactly ONE atomic pass (R2: 640K device atomics cost ~40us wherever hosted).
// NOTE: rank/cnt must not alias hb (written concurrently by gemm role).

#define GBM 64

__global__ __launch_bounds__(256) void count_gemm_kernel(
    const float* __restrict__ A, const uint32* __restrict__ Wh,
    uint32* __restrict__ hb, int M, int gemmBlocks,
    const int* __restrict__ dst, int* __restrict__ cnt,
    int* __restrict__ rank, int E) {
    __shared__ uint32 lds[64 * 68];  // As 17408B; reused as C staging in epilogue

    if (blockIdx.x >= gemmBlocks) {
        // ---- count role: in-degree + per-edge rank among its dst's edges ----
        int e = (blockIdx.x - gemmBlocks) * 256 + threadIdx.x;
        if (e < E) rank[e] = atomicAdd(&cnt[dst[e]], 1);
        return;
    }

    // ---- gemm role ----
    uint32* As = lds;  // [64 rows][68 dw]
    int tid = threadIdx.x;
    int row0 = blockIdx.x * GBM;

    // stage A tile: 64x128 fp32 -> fp16 (2048 float4, 8/thread, coalesced)
#pragma unroll
    for (int j = 0; j < 8; ++j) {
        int idx = tid + j * 256;
        int r = idx >> 5, c4 = idx & 31;
        float4 v = make_float4(0.f, 0.f, 0.f, 0.f);
        if (row0 + r < M) v = *(const float4*)&A[(size_t)(row0 + r) * D + c4 * 4];
        As[r * 68 + c4 * 2 + 0] = h2pair(v.x, v.y);
        As[r * 68 + c4 * 2 + 1] = h2pair(v.z, v.w);
    }
    __syncthreads();

    int wave = tid >> 6, lane = tid & 63;
    int quad = lane >> 4, l16 = lane & 15;
    int wr = (wave & 1) * 32;   // wave row base (2 m-tiles)
    int wc = (wave >> 1) * 64;  // wave col base (4 n-tiles)
    f32x4 acc[2][4];
#pragma unroll
    for (int mi = 0; mi < 2; ++mi)
#pragma unroll
        for (int ni = 0; ni < 4; ++ni) acc[mi][ni] = (f32x4){0.f, 0.f, 0.f, 0.f};

#pragma unroll
    for (int ks = 0; ks < 4; ++ks) {
        int kd = ks * 16 + quad * 4;  // dword offset of k0 + quad*8 fp16
        f16x8 a0 = *(f16x8*)&As[(wr + l16) * 68 + kd];
        f16x8 a1 = *(f16x8*)&As[(wr + 16 + l16) * 68 + kd];
        f16x8 b0 = *(const f16x8*)&Wh[(wc + l16) * 64 + kd];
        f16x8 b1 = *(const f16x8*)&Wh[(wc + 16 + l16) * 64 + kd];
        f16x8 b2 = *(const f16x8*)&Wh[(wc + 32 + l16) * 64 + kd];
        f16x8 b3 = *(const f16x8*)&Wh[(wc + 48 + l16) * 64 + kd];
        acc[0][0] = __builtin_amdgcn_mfma_f32_16x16x32_f16(a0, b0, acc[0][0], 0, 0, 0);
        acc[0][1] = __builtin_amdgcn_mfma_f32_16x16x32_f16(a0, b1, acc[0][1], 0, 0, 0);
        acc[0][2] = __builtin_amdgcn_mfma_f32_16x16x32_f16(a0, b2, acc[0][2], 0, 0, 0);
        acc[0][3] = __builtin_amdgcn_mfma_f32_16x16x32_f16(a0, b3, acc[0][3], 0, 0, 0);
        acc[1][0] = __builtin_amdgcn_mfma_f32_16x16x32_f16(a1, b0, acc[1][0], 0, 0, 0);
        acc[1][1] = __builtin_amdgcn_mfma_f32_16x16x32_f16(a1, b1, acc[1][1], 0, 0, 0);
        acc[1][2] = __builtin_amdgcn_mfma_f32_16x16x32_f16(a1, b2, acc[1][2], 0, 0, 0);
        acc[1][3] = __builtin_amdgcn_mfma_f32_16x16x32_f16(a1, b3, acc[1][3], 0, 0, 0);
    }
    __syncthreads();  // done reading As; reuse As region as C staging [64][128] fp16

    unsigned short* cs = (unsigned short*)lds;
#pragma unroll
    for (int mi = 0; mi < 2; ++mi)
#pragma unroll
        for (int ni = 0; ni < 4; ++ni)
#pragma unroll
            for (int r = 0; r < 4; ++r) {
                int row = wr + mi * 16 + quad * 4 + r;
                int col2 = wc + ni * 16 + l16;
                cs[row * 128 + col2] =
                    __builtin_bit_cast(unsigned short, (_Float16)acc[mi][ni][r]);
            }
    __syncthreads();
    // coalesced write-out: 64 rows x 16 uint4; C-staging row = 128 fp16 = 64 dwords
#pragma unroll
    for (int j = 0; j < 4; ++j) {
        int idx = tid + j * 256;
        int r = idx >> 4, q = idx & 15;
        if (row0 + r < M)
            *(uint4*)&hb[(size_t)(row0 + r) * 64 + q * 4] = *(uint4*)&lds[r * 64 + q * 4];
    }
}

// ---------------- CSR scan ----------------

// parallel scan, phase A. Fused: dinv.
__global__ __launch_bounds__(1024) void scanA_kernel(const int* __restrict__ cnt,
                                                     int* __restrict__ rowptr,
                                                     int* __restrict__ tot,
                                                     float* __restrict__ dinv, int n) {
    __shared__ int swave[16];
    int t = threadIdx.x;
    int lane = t & 63, wave = t >> 6;
    int i = blockIdx.x * 1024 + t;
    int orig = (i < n) ? cnt[i] : 0;
    int v = orig;
#pragma unroll
    for (int off = 1; off < 64; off <<= 1) {
        int u = __shfl_up(v, off, 64);
        if (lane >= off) v += u;
    }
    if (lane == 63) swave[wave] = v;
    __syncthreads();
    if (wave == 0) {
        int wv = (lane < 16) ? swave[lane] : 0;
#pragma unroll
        for (int off = 1; off < 16; off <<= 1) {
            int u = __shfl_up(wv, off, 64);
            if (lane >= off) wv += u;
        }
        if (lane < 16) swave[lane] = wv;
    }
    if (i < n) dinv[i] = rsqrtf((float)(orig + 1));  // deg = in-deg + self loop
    __syncthreads();
    int incl = v + ((wave > 0) ? swave[wave - 1] : 0);
    if (i < n) rowptr[i] = incl - orig;  // chunk-local exclusive
    if (t == 1023) tot[blockIdx.x] = incl;
}

// phase B: add chunk offsets (<=40 totals: serial per-block prefix is cheap)
__global__ __launch_bounds__(1024) void scanB_kernel(int* __restrict__ rowptr,
                                                     const int* __restrict__ tot,
                                                     int n, int nchunks) {
    __shared__ int soff;
    int b = blockIdx.x, t = threadIdx.x;
    if (t == 0) {
        int o = 0;
        for (int j = 0; j < b; ++j) o += tot[j];
        soff = o;
    }
    __syncthreads();
    int i = b * 1024 + t;
    if (i < n) rowptr[i] += soff;
    if (b == 0 && t == 0) {
        int o = 0;
        for (int j = 0; j < nchunks; ++j) o += tot[j];
        rowptr[n] = o;
    }
}

// ---------------- fused hb-prescale + CSR col scatter (one dispatch) ----------
// Scale role: hb[i] *= dinv[node] in place (hb' = dinv_s * (xW1)[s]) — the
// algebraic pre-scale that removes the 640K random dinv loads + per-edge
// multiply from BOTH gathers (R6 theory). 20MB stream, ~4us.
// Fill role: pure col scatter (4B/edge), as before.
__global__ __launch_bounds__(256) void scale_fill_kernel(
    uint32* __restrict__ hb, const float* __restrict__ dinv, int scaleBlocks, int n,
    const int* __restrict__ src, const int* __restrict__ dst,
    const int* __restrict__ rowptr, const int* __restrict__ rank,
    int* __restrict__ col, int E) {
    if (blockIdx.x >= scaleBlocks) {
        int e = (blockIdx.x - scaleBlocks) * 256 + threadIdx.x;
        if (e < E) col[rowptr[dst[e]] + rank[e]] = src[e];
        return;
    }
    int idx = blockIdx.x * 256 + threadIdx.x;  // uint4 index; 16 uint4 per row
    if (idx < n * 16) {
        int node = idx >> 4;
        float dv = dinv[node];
        uint4 v = ((uint4*)hb)[idx];
        v.x = h2pair(dv * hl(v.x), dv * hh(v.x));
        v.y = h2pair(dv * hl(v.y), dv * hh(v.y));
        v.z = h2pair(dv * hl(v.z), dv * hh(v.z));
        v.w = h2pair(dv * hl(v.w), dv * hh(v.w));
        ((uint4*)hb)[idx] = v;
    }
}

// ---------------- layer-1 aggregation (gather) + bias + ReLU -> fp16 h1' ------
// hb is PRE-SCALED by dinv_src: per-edge work is now ONE random row load + 4
// adds (no dinv[s] load, no weight multiply). H1 = relu(di*sum + b1); stores
// h1' = di*H1 so layer 2 gets the same pre-scaled form.
// Two-loop shape (x8 batch + scalar tail) is the measured optimum (R5).
// 128-thread blocks (R4 optimum; R6's 256 was ~neutral-negative).

__global__ __launch_bounds__(128) void agg_kernel(const uint32* __restrict__ hb,
                                                  const int* __restrict__ rowptr,
                                                  const int* __restrict__ col,
                                                  const float* __restrict__ dinv,
                                                  const float* __restrict__ bias,
                                                  uint32* __restrict__ h1, int n) {
    int tid = threadIdx.x;
    int lane32 = tid & 31;   // features 4*lane32 .. 4*lane32+3
    int slot = tid >> 5;     // 0..3
    int node = blockIdx.x * 4 + slot;
    if (node >= n) return;
    const uint2* __restrict__ h2 = (const uint2*)hb;  // 32 uint2 per row

    float di = dinv[node];
    uint2 su = h2[(size_t)node * 32 + lane32];  // hb'[node] = dinv_node*hb[node]
    float a0 = hl(su.x), a1 = hh(su.x);
    float a2 = hl(su.y), a3 = hh(su.y);

    int k = rowptr[node], end = rowptr[node + 1];
    for (; k + 8 <= end; k += 8) {
        uint2 v[8];
#pragma unroll
        for (int j = 0; j < 8; ++j) v[j] = h2[(size_t)col[k + j] * 32 + lane32];
#pragma unroll
        for (int j = 0; j < 8; ++j) {
            a0 += hl(v[j].x);
            a1 += hh(v[j].x);
            a2 += hl(v[j].y);
            a3 += hh(v[j].y);
        }
    }
    for (; k < end; ++k) {
        uint2 v = h2[(size_t)col[k] * 32 + lane32];
        a0 += hl(v.x);
        a1 += hh(v.x);
        a2 += hl(v.y);
        a3 += hh(v.y);
    }

    float4 b4 = ((const float4*)bias)[lane32];
    float r0 = fmaxf(fmaf(di, a0, b4.x), 0.f);
    float r1 = fmaxf(fmaf(di, a1, b4.y), 0.f);
    float r2 = fmaxf(fmaf(di, a2, b4.z), 0.f);
    float r3 = fmaxf(fmaf(di, a3, b4.w), 0.f);
    uint2 o;
    o.x = h2pair(di * r0, di * r1);  // store h1' = dinv*H1 (pre-scaled for layer 2)
    o.y = h2pair(di * r2, di * r3);
    ((uint2*)h1)[(size_t)node * 32 + lane32] = o;
}

// ---------------- layer-2 aggregation: materialize P2[node][128] fp32 ---------
// h1 is pre-scaled (h1' = dinv*H1): P2[d] = di * (sum_e h1'[src] + h1'[d]).
// Same gather structure as agg. Pooling is a separate streaming pass.

__global__ __launch_bounds__(128) void agg2_kernel(const uint32* __restrict__ h1,
                                                   const int* __restrict__ rowptr,
                                                   const int* __restrict__ col,
                                                   const float* __restrict__ dinv,
                                                   float* __restrict__ P2, int n) {
    int tid = threadIdx.x;
    int lane32 = tid & 31;
    int slot = tid >> 5;
    int node = blockIdx.x * 4 + slot;
    if (node >= n) return;
    const uint2* __restrict__ h2 = (const uint2*)h1;

    float di = dinv[node];
    uint2 su = h2[(size_t)node * 32 + lane32];
    float a0 = hl(su.x), a1 = hh(su.x);
    float a2 = hl(su.y), a3 = hh(su.y);

    int k = rowptr[node], end = rowptr[node + 1];
    for (; k + 8 <= end; k += 8) {
        uint2 v[8];
#pragma unroll
        for (int j = 0; j < 8; ++j) v[j] = h2[(size_t)col[k + j] * 32 + lane32];
#pragma unroll
        for (int j = 0; j < 8; ++j) {
            a0 += hl(v[j].x);
            a1 += hh(v[j].x);
            a2 += hl(v[j].y);
            a3 += hh(v[j].y);
        }
    }
    for (; k < end; ++k) {
        uint2 v = h2[(size_t)col[k] * 32 + lane32];
        a0 += hl(v.x);
        a1 += hh(v.x);
        a2 += hl(v.y);
        a3 += hh(v.y);
    }

    *(float4*)&P2[(size_t)node * D + lane32 * 4] =
        make_float4(di * a0, di * a1, di * a2, di * a3);
}

// ---------------- pooling: segmented streaming sum of P2 by graph -------------
#define PSL 16

__global__ __launch_bounds__(128) void pool_kernel(const float* __restrict__ P2,
                                                   const int* __restrict__ batch,
                                                   float* __restrict__ Ppart, int n) {
    __shared__ int srange[2];
    int t = threadIdx.x;
    int g = blockIdx.x >> 4;       // / PSL
    int kslice = blockIdx.x & 15;  // % PSL
    if (t == 0) {
        int lo = 0, hi = n;
        while (lo < hi) { int mid = (lo + hi) >> 1; if (batch[mid] < g) lo = mid + 1; else hi = mid; }
        srange[0] = lo;
        int g1 = g + 1;
        lo = 0; hi = n;
        while (lo < hi) { int mid = (lo + hi) >> 1; if (batch[mid] < g1) lo = mid + 1; else hi = mid; }
        srange[1] = lo;
    }
    __syncthreads();
    int lb = srange[0], cntg = srange[1] - srange[0];
    int a = lb + (int)(((long long)cntg * kslice) >> 4);
    int b = lb + (int)(((long long)cntg * (kslice + 1)) >> 4);

    float s = 0.f;
    int node = a;
    for (; node + 4 <= b; node += 4) {
        float v0 = P2[(size_t)(node + 0) * D + t];
        float v1 = P2[(size_t)(node + 1) * D + t];
        float v2 = P2[(size_t)(node + 2) * D + t];
        float v3 = P2[(size_t)(node + 3) * D + t];
        s += (v0 + v1) + (v2 + v3);
    }
    for (; node < b; ++node) s += P2[(size_t)node * D + t];
    Ppart[(size_t)blockIdx.x * D + t] = s;
}

// epilogue: out[g][f] = rinv_g * (sum_k Ppart[g*PSL+k]) @ W2 + b2
__global__ __launch_bounds__(256) void out_kernel(const float* __restrict__ Ppart,
                                                  const float* __restrict__ W2,
                                                  const float* __restrict__ b2,
                                                  const int* __restrict__ batch, int n,
                                                  float* __restrict__ out) {
    __shared__ float gs[D];
    __shared__ float part[2][D];
    __shared__ float srinv;
    int g = blockIdx.x, t = threadIdx.x;
    int f = t & 127, half = t >> 7;
    if (t == 0) {
        int lo = 0, hi = n;
        while (lo < hi) { int mid = (lo + hi) >> 1; if (batch[mid] < g) lo = mid + 1; else hi = mid; }
        int lb = lo;
        int g1 = g + 1;
        lo = 0; hi = n;
        while (lo < hi) { int mid = (lo + hi) >> 1; if (batch[mid] < g1) lo = mid + 1; else hi = mid; }
        int cg = lo - lb;
        srinv = (cg > 0) ? 1.0f / (float)cg : 0.0f;
    }
    float s = 0.f;
    int j0 = half * (PSL / 2);
#pragma unroll
    for (int j = j0; j < j0 + PSL / 2; ++j)
        s += Ppart[((size_t)g * PSL + j) * D + f];
    part[half][f] = s;
    __syncthreads();
    if (half == 0) gs[f] = part[0][f] + part[1][f];
    __syncthreads();
    float acc = 0.f;
    int k0 = half * (D / 2);
#pragma unroll 8
    for (int k = k0; k < k0 + D / 2; ++k) acc = fmaf(gs[k], W2[k * D + f], acc);
    part[half][f] = acc;
    __syncthreads();
    if (half == 0) {
        float a = part[0][f] + part[1][f];
        float r = srinv;
        out[g * D + f] = (r > 0.f) ? fmaf(a, r, b2[f]) : 0.f;  // empty graph -> 0 (matches ref)
    }
}

// ---------------- launcher ----------------

extern "C" void kernel_launch(void* const* d_in, const int* in_sizes, int n_in,
                              void* d_out, int out_size, void* d_ws, size_t ws_size,
                              hipStream_t stream) {
    const float* x  = (const float*)d_in[0];
    const int*   ei = (const int*)d_in[1];
    const int*   batch = (const int*)d_in[2];
    const float* W1 = (const float*)d_in[3];
    const float* b1 = (const float*)d_in[4];
    const float* W2 = (const float*)d_in[5];
    const float* b2 = (const float*)d_in[6];
    float* out = (float*)d_out;

    const int n = in_sizes[2];       // 40000 nodes
    const int E = in_sizes[1] / 2;   // 640000 edges
    const int* src = ei;             // edge_index[0] = message sources
    const int* dst = ei + E;         // edge_index[1] = aggregation targets

    // workspace carve-up (256B aligned); ws_size ~256MB (poison-fill evidence)
    char* ws = (char*)d_ws;
    size_t off = 0;
    auto carve = [&](size_t bytes) {
        size_t o = off;
        off = (off + bytes + 255) & ~(size_t)255;
        return (void*)(ws + o);
    };
    int*    cnt    = (int*)carve((size_t)n * 4);
    int*    rowptr = (int*)carve((size_t)(n + 1) * 4);
    float*  dinv   = (float*)carve((size_t)n * 4);
    int*    col    = (int*)carve((size_t)E * 4);                 // CSR col (2.56MB)
    uint32* hb     = (uint32*)carve((size_t)n * D * 2);          // fp16 feature rows (10.24MB)
    uint32* h1     = (uint32*)carve((size_t)n * D * 2);          // fp16 h1' rows (10.24MB)
    int*    tot    = (int*)carve(64 * 4);
    int*    rank   = (int*)carve((size_t)E * 4);                 // own carve: gemm role writes
                                                                 // hb WHILE count writes rank
    uint32* Wh     = (uint32*)carve((size_t)D * (D / 2) * 4);    // fp16 W1^T (32KB)
    float*  P2     = (float*)carve((size_t)n * D * 4);           // layer-2 rows fp32 (20.48MB)
    // Ppart (64*PSL*128*4 = 512KB) aliases hb: pool writes it strictly after
    // agg's last read of hb (agg2 reads h1, not hb).
    float*  Ppart  = (float*)hb;
    (void)ws_size;

    const int nchunks = (n + 1023) >> 10;

    // prep replaces the cnt memset dispatch; also builds fp16 W1^T for the gemm
    prep_kernel<<<(n + D * (D / 2) + 255) / 256, 256, 0, stream>>>(cnt, W1, Wh, n);

    // fused dispatch: gemm blocks first, then count blocks (gemm hides under
    // the single remaining 640K-atomic stretch)
    const int gemmBlocks = (n + GBM - 1) / GBM;
    const int countBlocks = (E + 255) / 256;
    count_gemm_kernel<<<gemmBlocks + countBlocks, 256, 0, stream>>>(
        x, Wh, hb, n, gemmBlocks, dst, cnt, rank, E);

    // CSR scan; then fused hb-prescale + col scatter
    scanA_kernel<<<nchunks, 1024, 0, stream>>>(cnt, rowptr, tot, dinv, n);
    scanB_kernel<<<nchunks, 1024, 0, stream>>>(rowptr, tot, n, nchunks);
    const int scaleBlocks = (n * 16 + 255) / 256;
    const int fillBlocks = (E + 255) / 256;
    scale_fill_kernel<<<scaleBlocks + fillBlocks, 256, 0, stream>>>(
        hb, dinv, scaleBlocks, n, src, dst, rowptr, rank, col, E);

    // layer 1 aggregation + b1 + ReLU -> h1' (fp16, pre-scaled)
    agg_kernel<<<(n + 3) / 4, 128, 0, stream>>>(hb, rowptr, col, dinv, b1, h1, n);

    // layer 2 aggregation (agg-style, materialized) + streaming pool + epilogue
    agg2_kernel<<<(n + 3) / 4, 128, 0, stream>>>(h1, rowptr, col, dinv, P2, n);
    pool_kernel<<<N_GRAPHS * PSL, 128, 0, stream>>>(P2, batch, Ppart, n);
    out_kernel<<<N_GRAPHS, 256, 0, stream>>>(Ppart, W2, b2, batch, n, out);
}

// Round 8
// 192.359 us; speedup vs baseline: 1.1912x; 1.0144x over previous
//
#include <hip/hip_runtime.h>

#define D 128
#define N_GRAPHS 64

typedef unsigned int uint32;
typedef __attribute__((ext_vector_type(8))) _Float16 f16x8;
typedef __attribute__((ext_vector_type(4))) float f32x4;

// fp16 helpers: dword holds 2 fp16 (low = elem 2i, high = elem 2i+1); RNE cvt
__device__ __forceinline__ float hl(uint32 u) {
    return (float)__builtin_bit_cast(_Float16, (unsigned short)(u & 0xFFFF));
}
__device__ __forceinline__ float hh(uint32 u) {
    return (float)__builtin_bit_cast(_Float16, (unsigned short)(u >> 16));
}
__device__ __forceinline__ uint32 h2pair(float a, float b) {
    unsigned short ua = __builtin_bit_cast(unsigned short, (_Float16)a);
    unsigned short ub = __builtin_bit_cast(unsigned short, (_Float16)b);
    return (uint32)ua | ((uint32)ub << 16);
}

// ---------------- prep: zero cnt + pre-convert W1 -> fp16 W^T ----------------
__global__ __launch_bounds__(256) void prep_kernel(int* __restrict__ cnt,
                                                   const float* __restrict__ W1,
                                                   uint32* __restrict__ Wh, int n) {
    int i = blockIdx.x * 256 + threadIdx.x;
    if (i < n) {
        cnt[i] = 0;
    } else if (i < n + D * (D / 2)) {
        int j = i - n;
        int nn = j & 127, kd = j >> 7;  // consecutive threads -> consecutive nn (coalesced reads)
        float v0 = W1[(size_t)(2 * kd) * D + nn];
        float v1 = W1[(size_t)(2 * kd + 1) * D + nn];
        Wh[nn * 64 + kd] = h2pair(v0, v1);
    }
}

// ---------------- fused count_rank + MFMA GEMM (independent, one dispatch) ----
// The 640K-atomic count stretch (~40us) hides the 15-20us gemm. CSR build keeps
// exactly ONE atomic pass (R2: 640K device atomics cost ~40us wherever hosted).
// NOTE: rank/cnt must not alias hb (written concurrently by gemm role).

#define GBM 64

__global__ __launch_bounds__(256) void count_gemm_kernel(
    const float* __restrict__ A, const uint32* __restrict__ Wh,
    uint32* __restrict__ hb, int M, int gemmBlocks,
    const int* __restrict__ dst, int* __restrict__ cnt,
    int* __restrict__ rank, int E) {
    __shared__ uint32 lds[64 * 68];  // As 17408B; reused as C staging in epilogue

    if (blockIdx.x >= gemmBlocks) {
        // ---- count role: in-degree + per-edge rank among its dst's edges ----
        int e = (blockIdx.x - gemmBlocks) * 256 + threadIdx.x;
        if (e < E) rank[e] = atomicAdd(&cnt[dst[e]], 1);
        return;
    }

    // ---- gemm role ----
    uint32* As = lds;  // [64 rows][68 dw]
    int tid = threadIdx.x;
    int row0 = blockIdx.x * GBM;

    // stage A tile: 64x128 fp32 -> fp16 (2048 float4, 8/thread, coalesced)
#pragma unroll
    for (int j = 0; j < 8; ++j) {
        int idx = tid + j * 256;
        int r = idx >> 5, c4 = idx & 31;
        float4 v = make_float4(0.f, 0.f, 0.f, 0.f);
        if (row0 + r < M) v = *(const float4*)&A[(size_t)(row0 + r) * D + c4 * 4];
        As[r * 68 + c4 * 2 + 0] = h2pair(v.x, v.y);
        As[r * 68 + c4 * 2 + 1] = h2pair(v.z, v.w);
    }
    __syncthreads();

    int wave = tid >> 6, lane = tid & 63;
    int quad = lane >> 4, l16 = lane & 15;
    int wr = (wave & 1) * 32;   // wave row base (2 m-tiles)
    int wc = (wave >> 1) * 64;  // wave col base (4 n-tiles)
    f32x4 acc[2][4];
#pragma unroll
    for (int mi = 0; mi < 2; ++mi)
#pragma unroll
        for (int ni = 0; ni < 4; ++ni) acc[mi][ni] = (f32x4){0.f, 0.f, 0.f, 0.f};

#pragma unroll
    for (int ks = 0; ks < 4; ++ks) {
        int kd = ks * 16 + quad * 4;  // dword offset of k0 + quad*8 fp16
        f16x8 a0 = *(f16x8*)&As[(wr + l16) * 68 + kd];
        f16x8 a1 = *(f16x8*)&As[(wr + 16 + l16) * 68 + kd];
        f16x8 b0 = *(const f16x8*)&Wh[(wc + l16) * 64 + kd];
        f16x8 b1 = *(const f16x8*)&Wh[(wc + 16 + l16) * 64 + kd];
        f16x8 b2 = *(const f16x8*)&Wh[(wc + 32 + l16) * 64 + kd];
        f16x8 b3 = *(const f16x8*)&Wh[(wc + 48 + l16) * 64 + kd];
        acc[0][0] = __builtin_amdgcn_mfma_f32_16x16x32_f16(a0, b0, acc[0][0], 0, 0, 0);
        acc[0][1] = __builtin_amdgcn_mfma_f32_16x16x32_f16(a0, b1, acc[0][1], 0, 0, 0);
        acc[0][2] = __builtin_amdgcn_mfma_f32_16x16x32_f16(a0, b2, acc[0][2], 0, 0, 0);
        acc[0][3] = __builtin_amdgcn_mfma_f32_16x16x32_f16(a0, b3, acc[0][3], 0, 0, 0);
        acc[1][0] = __builtin_amdgcn_mfma_f32_16x16x32_f16(a1, b0, acc[1][0], 0, 0, 0);
        acc[1][1] = __builtin_amdgcn_mfma_f32_16x16x32_f16(a1, b1, acc[1][1], 0, 0, 0);
        acc[1][2] = __builtin_amdgcn_mfma_f32_16x16x32_f16(a1, b2, acc[1][2], 0, 0, 0);
        acc[1][3] = __builtin_amdgcn_mfma_f32_16x16x32_f16(a1, b3, acc[1][3], 0, 0, 0);
    }
    __syncthreads();  // done reading As; reuse As region as C staging [64][128] fp16

    unsigned short* cs = (unsigned short*)lds;
#pragma unroll
    for (int mi = 0; mi < 2; ++mi)
#pragma unroll
        for (int ni = 0; ni < 4; ++ni)
#pragma unroll
            for (int r = 0; r < 4; ++r) {
                int row = wr + mi * 16 + quad * 4 + r;
                int col2 = wc + ni * 16 + l16;
                cs[row * 128 + col2] =
                    __builtin_bit_cast(unsigned short, (_Float16)acc[mi][ni][r]);
            }
    __syncthreads();
    // coalesced write-out: 64 rows x 16 uint4; C-staging row = 128 fp16 = 64 dwords
#pragma unroll
    for (int j = 0; j < 4; ++j) {
        int idx = tid + j * 256;
        int r = idx >> 4, q = idx & 15;
        if (row0 + r < M)
            *(uint4*)&hb[(size_t)(row0 + r) * 64 + q * 4] = *(uint4*)&lds[r * 64 + q * 4];
    }
}

// ---------------- CSR scan ----------------

// parallel scan, phase A. Fused: dinv.
__global__ __launch_bounds__(1024) void scanA_kernel(const int* __restrict__ cnt,
                                                     int* __restrict__ rowptr,
                                                     int* __restrict__ tot,
                                                     float* __restrict__ dinv, int n) {
    __shared__ int swave[16];
    int t = threadIdx.x;
    int lane = t & 63, wave = t >> 6;
    int i = blockIdx.x * 1024 + t;
    int orig = (i < n) ? cnt[i] : 0;
    int v = orig;
#pragma unroll
    for (int off = 1; off < 64; off <<= 1) {
        int u = __shfl_up(v, off, 64);
        if (lane >= off) v += u;
    }
    if (lane == 63) swave[wave] = v;
    __syncthreads();
    if (wave == 0) {
        int wv = (lane < 16) ? swave[lane] : 0;
#pragma unroll
        for (int off = 1; off < 16; off <<= 1) {
            int u = __shfl_up(wv, off, 64);
            if (lane >= off) wv += u;
        }
        if (lane < 16) swave[lane] = wv;
    }
    if (i < n) dinv[i] = rsqrtf((float)(orig + 1));  // deg = in-deg + self loop
    __syncthreads();
    int incl = v + ((wave > 0) ? swave[wave - 1] : 0);
    if (i < n) rowptr[i] = incl - orig;  // chunk-local exclusive
    if (t == 1023) tot[blockIdx.x] = incl;
}

// phase B: add chunk offsets (<=40 totals: serial per-block prefix is cheap)
__global__ __launch_bounds__(1024) void scanB_kernel(int* __restrict__ rowptr,
                                                     const int* __restrict__ tot,
                                                     int n, int nchunks) {
    __shared__ int soff;
    int b = blockIdx.x, t = threadIdx.x;
    if (t == 0) {
        int o = 0;
        for (int j = 0; j < b; ++j) o += tot[j];
        soff = o;
    }
    __syncthreads();
    int i = b * 1024 + t;
    if (i < n) rowptr[i] += soff;
    if (b == 0 && t == 0) {
        int o = 0;
        for (int j = 0; j < nchunks; ++j) o += tot[j];
        rowptr[n] = o;
    }
}

// ---------------- fused hb-prescale + CSR col scatter (one dispatch) ----------
// Scale role: hb[i] *= dinv[node] in place (hb' = dinv_s * (xW1)[s]).
// Fill role: pure col scatter (4B/edge).
__global__ __launch_bounds__(256) void scale_fill_kernel(
    uint32* __restrict__ hb, const float* __restrict__ dinv, int scaleBlocks, int n,
    const int* __restrict__ src, const int* __restrict__ dst,
    const int* __restrict__ rowptr, const int* __restrict__ rank,
    int* __restrict__ col, int E) {
    if (blockIdx.x >= scaleBlocks) {
        int e = (blockIdx.x - scaleBlocks) * 256 + threadIdx.x;
        if (e < E) col[rowptr[dst[e]] + rank[e]] = src[e];
        return;
    }
    int idx = blockIdx.x * 256 + threadIdx.x;  // uint4 index; 16 uint4 per row
    if (idx < n * 16) {
        int node = idx >> 4;
        float dv = dinv[node];
        uint4 v = ((uint4*)hb)[idx];
        v.x = h2pair(dv * hl(v.x), dv * hh(v.x));
        v.y = h2pair(dv * hl(v.y), dv * hh(v.y));
        v.z = h2pair(dv * hl(v.z), dv * hh(v.z));
        v.w = h2pair(dv * hl(v.w), dv * hh(v.w));
        ((uint4*)hb)[idx] = v;
    }
}

// ---------------- layer-1 aggregation (gather) + bias + ReLU -> fp16 h1' ------
// R7 lesson: gathers are row-load LATENCY-bound, not issue-bound (dinv-removal
// was neutral). Fix the latency-hiding limit: 16-lane groups x uint4 (16B/lane)
// — one VMEM instruction now covers 4 nodes x 256B = 1KB (vs 512B at 32-lane
// uint2), doubling row-bytes in flight per wave at the same 8-deep unroll.
// Two-loop shape (x8 batch + scalar tail) is the measured optimum (R5).

__global__ __launch_bounds__(128) void agg_kernel(const uint32* __restrict__ hb,
                                                  const int* __restrict__ rowptr,
                                                  const int* __restrict__ col,
                                                  const float* __restrict__ dinv,
                                                  const float* __restrict__ bias,
                                                  uint32* __restrict__ h1, int n) {
    int tid = threadIdx.x;
    int lane16 = tid & 15;   // features 8*lane16 .. 8*lane16+7 (16B)
    int slot = tid >> 4;     // 0..7
    int node = blockIdx.x * 8 + slot;
    if (node >= n) return;
    const uint4* __restrict__ h4 = (const uint4*)hb;  // 16 uint4 per row

    float di = dinv[node];
    uint4 su = h4[(size_t)node * 16 + lane16];  // hb'[node] = dinv_node*hb[node]
    float a0 = hl(su.x), a1 = hh(su.x), a2 = hl(su.y), a3 = hh(su.y);
    float a4 = hl(su.z), a5 = hh(su.z), a6 = hl(su.w), a7 = hh(su.w);

    int k = rowptr[node], end = rowptr[node + 1];
    for (; k + 8 <= end; k += 8) {
        uint4 v[8];
#pragma unroll
        for (int j = 0; j < 8; ++j) v[j] = h4[(size_t)col[k + j] * 16 + lane16];
#pragma unroll
        for (int j = 0; j < 8; ++j) {
            a0 += hl(v[j].x); a1 += hh(v[j].x);
            a2 += hl(v[j].y); a3 += hh(v[j].y);
            a4 += hl(v[j].z); a5 += hh(v[j].z);
            a6 += hl(v[j].w); a7 += hh(v[j].w);
        }
    }
    for (; k < end; ++k) {
        uint4 v = h4[(size_t)col[k] * 16 + lane16];
        a0 += hl(v.x); a1 += hh(v.x);
        a2 += hl(v.y); a3 += hh(v.y);
        a4 += hl(v.z); a5 += hh(v.z);
        a6 += hl(v.w); a7 += hh(v.w);
    }

    float4 b4a = ((const float4*)bias)[2 * lane16];
    float4 b4b = ((const float4*)bias)[2 * lane16 + 1];
    float r0 = fmaxf(fmaf(di, a0, b4a.x), 0.f);
    float r1 = fmaxf(fmaf(di, a1, b4a.y), 0.f);
    float r2 = fmaxf(fmaf(di, a2, b4a.z), 0.f);
    float r3 = fmaxf(fmaf(di, a3, b4a.w), 0.f);
    float r4 = fmaxf(fmaf(di, a4, b4b.x), 0.f);
    float r5 = fmaxf(fmaf(di, a5, b4b.y), 0.f);
    float r6 = fmaxf(fmaf(di, a6, b4b.z), 0.f);
    float r7 = fmaxf(fmaf(di, a7, b4b.w), 0.f);
    uint4 o;
    o.x = h2pair(di * r0, di * r1);  // store h1' = dinv*H1 (pre-scaled for layer 2)
    o.y = h2pair(di * r2, di * r3);
    o.z = h2pair(di * r4, di * r5);
    o.w = h2pair(di * r6, di * r7);
    ((uint4*)h1)[(size_t)node * 16 + lane16] = o;
}

// ---------------- layer-2 aggregation: materialize P2[node][128] fp32 ---------
// h1 is pre-scaled (h1' = dinv*H1): P2[d] = di * (sum_e h1'[src] + h1'[d]).
// Same 16-lane/uint4 gather structure as agg.

__global__ __launch_bounds__(128) void agg2_kernel(const uint32* __restrict__ h1,
                                                   const int* __restrict__ rowptr,
                                                   const int* __restrict__ col,
                                                   const float* __restrict__ dinv,
                                                   float* __restrict__ P2, int n) {
    int tid = threadIdx.x;
    int lane16 = tid & 15;
    int slot = tid >> 4;
    int node = blockIdx.x * 8 + slot;
    if (node >= n) return;
    const uint4* __restrict__ h4 = (const uint4*)h1;

    float di = dinv[node];
    uint4 su = h4[(size_t)node * 16 + lane16];
    float a0 = hl(su.x), a1 = hh(su.x), a2 = hl(su.y), a3 = hh(su.y);
    float a4 = hl(su.z), a5 = hh(su.z), a6 = hl(su.w), a7 = hh(su.w);

    int k = rowptr[node], end = rowptr[node + 1];
    for (; k + 8 <= end; k += 8) {
        uint4 v[8];
#pragma unroll
        for (int j = 0; j < 8; ++j) v[j] = h4[(size_t)col[k + j] * 16 + lane16];
#pragma unroll
        for (int j = 0; j < 8; ++j) {
            a0 += hl(v[j].x); a1 += hh(v[j].x);
            a2 += hl(v[j].y); a3 += hh(v[j].y);
            a4 += hl(v[j].z); a5 += hh(v[j].z);
            a6 += hl(v[j].w); a7 += hh(v[j].w);
        }
    }
    for (; k < end; ++k) {
        uint4 v = h4[(size_t)col[k] * 16 + lane16];
        a0 += hl(v.x); a1 += hh(v.x);
        a2 += hl(v.y); a3 += hh(v.y);
        a4 += hl(v.z); a5 += hh(v.z);
        a6 += hl(v.w); a7 += hh(v.w);
    }

    float* p = &P2[(size_t)node * D + lane16 * 8];
    *(float4*)&p[0] = make_float4(di * a0, di * a1, di * a2, di * a3);
    *(float4*)&p[4] = make_float4(di * a4, di * a5, di * a6, di * a7);
}

// ---------------- pooling: segmented streaming sum of P2 by graph -------------
#define PSL 16

__global__ __launch_bounds__(128) void pool_kernel(const float* __restrict__ P2,
                                                   const int* __restrict__ batch,
                                                   float* __restrict__ Ppart, int n) {
    __shared__ int srange[2];
    int t = threadIdx.x;
    int g = blockIdx.x >> 4;       // / PSL
    int kslice = blockIdx.x & 15;  // % PSL
    if (t == 0) {
        int lo = 0, hi = n;
        while (lo < hi) { int mid = (lo + hi) >> 1; if (batch[mid] < g) lo = mid + 1; else hi = mid; }
        srange[0] = lo;
        int g1 = g + 1;
        lo = 0; hi = n;
        while (lo < hi) { int mid = (lo + hi) >> 1; if (batch[mid] < g1) lo = mid + 1; else hi = mid; }
        srange[1] = lo;
    }
    __syncthreads();
    int lb = srange[0], cntg = srange[1] - srange[0];
    int a = lb + (int)(((long long)cntg * kslice) >> 4);
    int b = lb + (int)(((long long)cntg * (kslice + 1)) >> 4);

    float s = 0.f;
    int node = a;
    for (; node + 4 <= b; node += 4) {
        float v0 = P2[(size_t)(node + 0) * D + t];
        float v1 = P2[(size_t)(node + 1) * D + t];
        float v2 = P2[(size_t)(node + 2) * D + t];
        float v3 = P2[(size_t)(node + 3) * D + t];
        s += (v0 + v1) + (v2 + v3);
    }
    for (; node < b; ++node) s += P2[(size_t)node * D + t];
    Ppart[(size_t)blockIdx.x * D + t] = s;
}

// epilogue: out[g][f] = rinv_g * (sum_k Ppart[g*PSL+k]) @ W2 + b2
__global__ __launch_bounds__(256) void out_kernel(const float* __restrict__ Ppart,
                                                  const float* __restrict__ W2,
                                                  const float* __restrict__ b2,
                                                  const int* __restrict__ batch, int n,
                                                  float* __restrict__ out) {
    __shared__ float gs[D];
    __shared__ float part[2][D];
    __shared__ float srinv;
    int g = blockIdx.x, t = threadIdx.x;
    int f = t & 127, half = t >> 7;
    if (t == 0) {
        int lo = 0, hi = n;
        while (lo < hi) { int mid = (lo + hi) >> 1; if (batch[mid] < g) lo = mid + 1; else hi = mid; }
        int lb = lo;
        int g1 = g + 1;
        lo = 0; hi = n;
        while (lo < hi) { int mid = (lo + hi) >> 1; if (batch[mid] < g1) lo = mid + 1; else hi = mid; }
        int cg = lo - lb;
        srinv = (cg > 0) ? 1.0f / (float)cg : 0.0f;
    }
    float s = 0.f;
    int j0 = half * (PSL / 2);
#pragma unroll
    for (int j = j0; j < j0 + PSL / 2; ++j)
        s += Ppart[((size_t)g * PSL + j) * D + f];
    part[half][f] = s;
    __syncthreads();
    if (half == 0) gs[f] = part[0][f] + part[1][f];
    __syncthreads();
    float acc = 0.f;
    int k0 = half * (D / 2);
#pragma unroll 8
    for (int k = k0; k < k0 + D / 2; ++k) acc = fmaf(gs[k], W2[k * D + f], acc);
    part[half][f] = acc;
    __syncthreads();
    if (half == 0) {
        float a = part[0][f] + part[1][f];
        float r = srinv;
        out[g * D + f] = (r > 0.f) ? fmaf(a, r, b2[f]) : 0.f;  // empty graph -> 0 (matches ref)
    }
}

// ---------------- launcher ----------------

extern "C" void kernel_launch(void* const* d_in, const int* in_sizes, int n_in,
                              void* d_out, int out_size, void* d_ws, size_t ws_size,
                              hipStream_t stream) {
    const float* x  = (const float*)d_in[0];
    const int*   ei = (const int*)d_in[1];
    const int*   batch = (const int*)d_in[2];
    const float* W1 = (const float*)d_in[3];
    const float* b1 = (const float*)d_in[4];
    const float* W2 = (const float*)d_in[5];
    const float* b2 = (const float*)d_in[6];
    float* out = (float*)d_out;

    const int n = in_sizes[2];       // 40000 nodes
    const int E = in_sizes[1] / 2;   // 640000 edges
    const int* src = ei;             // edge_index[0] = message sources
    const int* dst = ei + E;         // edge_index[1] = aggregation targets

    // workspace carve-up (256B aligned); ws_size ~256MB (poison-fill evidence)
    char* ws = (char*)d_ws;
    size_t off = 0;
    auto carve = [&](size_t bytes) {
        size_t o = off;
        off = (off + bytes + 255) & ~(size_t)255;
        return (void*)(ws + o);
    };
    int*    cnt    = (int*)carve((size_t)n * 4);
    int*    rowptr = (int*)carve((size_t)(n + 1) * 4);
    float*  dinv   = (float*)carve((size_t)n * 4);
    int*    col    = (int*)carve((size_t)E * 4);                 // CSR col (2.56MB)
    uint32* hb     = (uint32*)carve((size_t)n * D * 2);          // fp16 feature rows (10.24MB)
    uint32* h1     = (uint32*)carve((size_t)n * D * 2);          // fp16 h1' rows (10.24MB)
    int*    tot    = (int*)carve(64 * 4);
    int*    rank   = (int*)carve((size_t)E * 4);                 // own carve: gemm role writes
                                                                 // hb WHILE count writes rank
    uint32* Wh     = (uint32*)carve((size_t)D * (D / 2) * 4);    // fp16 W1^T (32KB)
    float*  P2     = (float*)carve((size_t)n * D * 4);           // layer-2 rows fp32 (20.48MB)
    // Ppart (64*PSL*128*4 = 512KB) aliases hb: pool writes it strictly after
    // agg's last read of hb (agg2 reads h1, not hb).
    float*  Ppart  = (float*)hb;
    (void)ws_size;

    const int nchunks = (n + 1023) >> 10;

    // prep replaces the cnt memset dispatch; also builds fp16 W1^T for the gemm
    prep_kernel<<<(n + D * (D / 2) + 255) / 256, 256, 0, stream>>>(cnt, W1, Wh, n);

    // fused dispatch: gemm blocks first, then count blocks (gemm hides under
    // the single remaining 640K-atomic stretch)
    const int gemmBlocks = (n + GBM - 1) / GBM;
    const int countBlocks = (E + 255) / 256;
    count_gemm_kernel<<<gemmBlocks + countBlocks, 256, 0, stream>>>(
        x, Wh, hb, n, gemmBlocks, dst, cnt, rank, E);

    // CSR scan; then fused hb-prescale + col scatter
    scanA_kernel<<<nchunks, 1024, 0, stream>>>(cnt, rowptr, tot, dinv, n);
    scanB_kernel<<<nchunks, 1024, 0, stream>>>(rowptr, tot, n, nchunks);
    const int scaleBlocks = (n * 16 + 255) / 256;
    const int fillBlocks = (E + 255) / 256;
    scale_fill_kernel<<<scaleBlocks + fillBlocks, 256, 0, stream>>>(
        hb, dinv, scaleBlocks, n, src, dst, rowptr, rank, col, E);

    // layer 1 aggregation + b1 + ReLU -> h1' (fp16, pre-scaled)
    agg_kernel<<<(n + 7) / 8, 128, 0, stream>>>(hb, rowptr, col, dinv, b1, h1, n);

    // layer 2 aggregation (agg-style, materialized) + streaming pool + epilogue
    agg2_kernel<<<(n + 7) / 8, 128, 0, stream>>>(h1, rowptr, col, dinv, P2, n);
    pool_kernel<<<N_GRAPHS * PSL, 128, 0, stream>>>(P2, batch, Ppart, n);
    out_kernel<<<N_GRAPHS, 256, 0, stream>>>(Ppart, W2, b2, batch, n, out);
}